// Round 1
// baseline (365.089 us; speedup 1.0000x reference)
//
#include <hip/hip_runtime.h>
#include <math.h>

#define LL 2048
#define CC 128
#define UU 40
#define NT 256
#define NW 4
#define EPSF 1e-5f

__device__ __forceinline__ float blockSum(float v, volatile float* scr) {
#pragma unroll
    for (int off = 1; off < 64; off <<= 1) v += __shfl_xor(v, off, 64);
    const int lane = threadIdx.x & 63, wid = threadIdx.x >> 6;
    __syncthreads();
    if (lane == 0) scr[wid] = v;
    __syncthreads();
    return scr[0] + scr[1] + scr[2] + scr[3];
}
__device__ __forceinline__ float blockMax(float v, volatile float* scr) {
#pragma unroll
    for (int off = 1; off < 64; off <<= 1) v = fmaxf(v, __shfl_xor(v, off, 64));
    const int lane = threadIdx.x & 63, wid = threadIdx.x >> 6;
    __syncthreads();
    if (lane == 0) scr[wid] = v;
    __syncthreads();
    return fmaxf(fmaxf(scr[0], scr[1]), fmaxf(scr[2], scr[3]));
}
__device__ __forceinline__ float blockMin(float v, volatile float* scr) {
#pragma unroll
    for (int off = 1; off < 64; off <<= 1) v = fminf(v, __shfl_xor(v, off, 64));
    const int lane = threadIdx.x & 63, wid = threadIdx.x >> 6;
    __syncthreads();
    if (lane == 0) scr[wid] = v;
    __syncthreads();
    return fminf(fminf(scr[0], scr[1]), fminf(scr[2], scr[3]));
}

__global__ __launch_bounds__(NT) void informer_kernel(
    const float* __restrict__ x,
    const float* __restrict__ pWq, const float* __restrict__ pbq,
    const float* __restrict__ pWk, const float* __restrict__ pbk,
    const float* __restrict__ pWv, const float* __restrict__ pbv,
    const float* __restrict__ pWo, const float* __restrict__ pbo,
    const float* __restrict__ pw1, const float* __restrict__ pb1,
    const float* __restrict__ pw2, const float* __restrict__ pb2,
    const float* __restrict__ pg1, const float* __restrict__ pbe1,
    const float* __restrict__ pg2, const float* __restrict__ pbe2,
    const int* __restrict__ idx,
    float* __restrict__ out)
{
    const int tid  = threadIdx.x;
    const int lane = tid & 63;
    const int wid  = tid >> 6;
    const int blk  = blockIdx.x;     // b*CC + c
    const int b    = blk >> 7;       // / 128
    const int c    = blk & (CC - 1);

    __shared__ float s_xc[LL];
    __shared__ float s_k[LL];
    __shared__ float s_v[LL];
    __shared__ float s_ctx[LL];
    __shared__ float s_red[NW];
    __shared__ double s_rval[NW];
    __shared__ int    s_ridx[NW];
    __shared__ int    s_top[UU];
    __shared__ float  s_upd[UU];
    __shared__ int    s_win;

    const float Wq = *pWq, bq = *pbq, Wk = *pWk, bk = *pbk;
    const float Wv = *pWv, bv = *pbv, Wo = *pWo, bo = *pbo;
    const float w1 = *pw1, b1 = *pb1, w2 = *pw2, b2 = *pb2;
    const float g1 = *pg1, be1 = *pbe1, g2 = *pg2, be2 = *pbe2;

    // ---- step 1: load x row (strided), compute k,v; accumulate v-sum, k-min/max
    float vsum = 0.f, kmn = 3.4e38f, kmx = -3.4e38f;
    const float* xrow = x + (size_t)b * LL * CC + c;
    for (int l = tid; l < LL; l += NT) {
        float xv = xrow[(size_t)l * CC];
        s_xc[l] = xv;
        float kv = __fadd_rn(__fmul_rn(xv, Wk), bk);
        float vv = __fadd_rn(__fmul_rn(xv, Wv), bv);
        s_k[l] = kv;
        s_v[l] = vv;
        vsum += vv;
        kmn = fminf(kmn, kv);
        kmx = fmaxf(kmx, kv);
    }
    // barriers inside the reducers also make s_k/s_v/s_xc visible
    const float vmean  = blockSum(vsum, s_red) * (1.f / (float)LL);
    const float kmxAll = blockMax(kmx, s_red);
    const float kmnAll = blockMin(kmn, s_red);

    // ---- step 3: M[l] = max_u(q*Ks) - q*sum_u(Ks)/L   (f64 for stable ordering)
    double mloc[8];  // element l = tid + 256*j
#pragma unroll
    for (int j = 0; j < 8; ++j) {
        const int l = tid + NT * j;
        const float qv = __fadd_rn(__fmul_rn(s_xc[l], Wq), bq);
        const double qd = (double)qv;
        const int* row = idx + l * UU;
        float kmaxs = -3.4e38f, kmins = 3.4e38f;
        double ssum = 0.0;
#pragma unroll 8
        for (int u = 0; u < UU; ++u) {
            float kv = s_k[row[u]];
            kmaxs = fmaxf(kmaxs, kv);
            kmins = fminf(kmins, kv);
            ssum += (double)kv;
        }
        double qmax = (qd >= 0.0) ? qd * (double)kmaxs : qd * (double)kmins;
        mloc[j] = qmax - qd * ssum * (1.0 / (double)LL);
    }
    __syncthreads();

    // ---- step 4: top-UU via iterative argmax (ties -> lower index)
    for (int t = 0; t < UU; ++t) {
        double bval = -1e300;
        int bi = LL;
#pragma unroll
        for (int j = 0; j < 8; ++j) {
            const int l = tid + NT * j;
            if (mloc[j] > bval || (mloc[j] == bval && l < bi)) { bval = mloc[j]; bi = l; }
        }
#pragma unroll
        for (int off = 1; off < 64; off <<= 1) {
            double ov = __shfl_xor(bval, off, 64);
            int    oi = __shfl_xor(bi,   off, 64);
            if (ov > bval || (ov == bval && oi < bi)) { bval = ov; bi = oi; }
        }
        if (lane == 0) { s_rval[wid] = bval; s_ridx[wid] = bi; }
        __syncthreads();
        if (tid == 0) {
            double wv = s_rval[0]; int wi = s_ridx[0];
            for (int w = 1; w < NW; ++w)
                if (s_rval[w] > wv || (s_rval[w] == wv && s_ridx[w] < wi)) { wv = s_rval[w]; wi = s_ridx[w]; }
            s_top[t] = wi;
            s_win = wi;
        }
        __syncthreads();
        const int wi = s_win;
        if ((wi & (NT - 1)) == tid) {
            const int j = wi >> 8;
#pragma unroll
            for (int jj = 0; jj < 8; ++jj) if (jj == j) mloc[jj] = -1e300;
        }
    }
    __syncthreads();

    // ---- step 5: upd[u] = softmax(q_p * k) . v   — one u per wave, 10 rounds
    for (int r = 0; r < UU / NW; ++r) {
        const int u = r * NW + wid;
        const int p = s_top[u];
        const float qp = __fadd_rn(__fmul_rn(s_xc[p], Wq), bq);
        const float smax = (qp >= 0.f) ? qp * kmxAll : qp * kmnAll;
        float se = 0.f, sev = 0.f;
        for (int l = lane; l < LL; l += 64) {
            float e = __expf(qp * s_k[l] - smax);
            se += e;
            sev = fmaf(e, s_v[l], sev);
        }
#pragma unroll
        for (int off = 1; off < 64; off <<= 1) {
            se  += __shfl_xor(se,  off, 64);
            sev += __shfl_xor(sev, off, 64);
        }
        if (lane == 0) s_upd[u] = sev / se;
    }
    __syncthreads();

    // ---- step 6: ctx = vmean, scatter upd; t = xc + ctx*Wo + bo; LN1
    for (int l = tid; l < LL; l += NT) s_ctx[l] = vmean;
    __syncthreads();
    if (tid < UU) s_ctx[s_top[tid]] = s_upd[tid];
    __syncthreads();

    float lsum = 0.f;
    for (int l = tid; l < LL; l += NT) {
        float tv = s_xc[l] + __fadd_rn(__fmul_rn(s_ctx[l], Wo), bo);
        s_ctx[l] = tv;
        lsum += tv;
    }
    const float mean1 = blockSum(lsum, s_red) * (1.f / (float)LL);
    float lss = 0.f;
    for (int l = tid; l < LL; l += NT) { float d = s_ctx[l] - mean1; lss += d * d; }
    const float var1 = blockSum(lss, s_red) * (1.f / (float)LL);
    const float rs1 = rsqrtf(var1 + EPSF);

    // ---- step 7: x1 -> gelu FFN -> z; LN2 -> out
    float lsum2 = 0.f;
    for (int l = tid; l < LL; l += NT) {
        float x1 = (s_ctx[l] - mean1) * rs1 * g1 + be1;
        float a  = x1 * w1 + b1;
        float y  = 0.5f * a * (1.f + erff(a * 0.70710678118654752f));
        y = y * w2 + b2;
        float z = x1 + y;
        s_ctx[l] = z;
        lsum2 += z;
    }
    const float mean2 = blockSum(lsum2, s_red) * (1.f / (float)LL);
    float lss2 = 0.f;
    for (int l = tid; l < LL; l += NT) { float d = s_ctx[l] - mean2; lss2 += d * d; }
    const float var2 = blockSum(lss2, s_red) * (1.f / (float)LL);
    const float rs2 = rsqrtf(var2 + EPSF);

    float* orow = out + (size_t)b * LL * CC + c;
    for (int l = tid; l < LL; l += NT) {
        orow[(size_t)l * CC] = (s_ctx[l] - mean2) * rs2 * g2 + be2;
    }
}

extern "C" void kernel_launch(void* const* d_in, const int* in_sizes, int n_in,
                              void* d_out, int out_size, void* d_ws, size_t ws_size,
                              hipStream_t stream) {
    const float* x   = (const float*)d_in[0];
    const float* Wq  = (const float*)d_in[1];
    const float* bq  = (const float*)d_in[2];
    const float* Wk  = (const float*)d_in[3];
    const float* bk  = (const float*)d_in[4];
    const float* Wv  = (const float*)d_in[5];
    const float* bv  = (const float*)d_in[6];
    const float* Wo  = (const float*)d_in[7];
    const float* bo  = (const float*)d_in[8];
    const float* w1  = (const float*)d_in[9];
    const float* b1  = (const float*)d_in[10];
    const float* w2  = (const float*)d_in[11];
    const float* b2  = (const float*)d_in[12];
    const float* g1  = (const float*)d_in[13];
    const float* be1 = (const float*)d_in[14];
    const float* g2  = (const float*)d_in[15];
    const float* be2 = (const float*)d_in[16];
    const int*   idx = (const int*)d_in[17];
    float* out = (float*)d_out;

    dim3 grid(16 * CC);   // one block per (b, c)
    dim3 block(NT);
    informer_kernel<<<grid, block, 0, stream>>>(
        x, Wq, bq, Wk, bk, Wv, bv, Wo, bo, w1, b1, w2, b2,
        g1, be1, g2, be2, idx, out);
}

// Round 3
// 350.168 us; speedup vs baseline: 1.0426x; 1.0426x over previous
//
#include <hip/hip_runtime.h>
#include <math.h>

#define LL 2048
#define CC 128
#define BB 16
#define UU 40
#define NT 256
#define NW 4
#define EPSF 1e-5f

__device__ __forceinline__ float blockSum(float v, volatile float* scr) {
#pragma unroll
    for (int off = 1; off < 64; off <<= 1) v += __shfl_xor(v, off, 64);
    const int lane = threadIdx.x & 63, wid = threadIdx.x >> 6;
    __syncthreads();
    if (lane == 0) scr[wid] = v;
    __syncthreads();
    return scr[0] + scr[1] + scr[2] + scr[3];
}
__device__ __forceinline__ float blockMax(float v, volatile float* scr) {
#pragma unroll
    for (int off = 1; off < 64; off <<= 1) v = fmaxf(v, __shfl_xor(v, off, 64));
    const int lane = threadIdx.x & 63, wid = threadIdx.x >> 6;
    __syncthreads();
    if (lane == 0) scr[wid] = v;
    __syncthreads();
    return fmaxf(fmaxf(scr[0], scr[1]), fmaxf(scr[2], scr[3]));
}
__device__ __forceinline__ float blockMin(float v, volatile float* scr) {
#pragma unroll
    for (int off = 1; off < 64; off <<= 1) v = fminf(v, __shfl_xor(v, off, 64));
    const int lane = threadIdx.x & 63, wid = threadIdx.x >> 6;
    __syncthreads();
    if (lane == 0) scr[wid] = v;
    __syncthreads();
    return fminf(fminf(scr[0], scr[1]), fminf(scr[2], scr[3]));
}

// ---------------- transpose kernels ----------------
// x [B,L,C] -> xT [B,C,L]
__global__ __launch_bounds__(256) void transpose_in(const float* __restrict__ in,
                                                    float* __restrict__ outp) {
    __shared__ float t[32][33];
    const int b  = blockIdx.z;
    const int c0 = blockIdx.x * 32, l0 = blockIdx.y * 32;
    const int lx = threadIdx.x, ly = threadIdx.y;
    const float* base = in + ((size_t)b * LL + l0) * CC + c0;
#pragma unroll
    for (int i = 0; i < 4; ++i) t[ly + i * 8][lx] = base[(size_t)(ly + i * 8) * CC + lx];
    __syncthreads();
    float* obase = outp + ((size_t)b * CC + c0) * LL + l0;
#pragma unroll
    for (int i = 0; i < 4; ++i) obase[(size_t)(ly + i * 8) * LL + lx] = t[lx][ly + i * 8];
}
// outT [B,C,L] -> out [B,L,C]
__global__ __launch_bounds__(256) void transpose_out(const float* __restrict__ in,
                                                     float* __restrict__ outp) {
    __shared__ float t[32][33];
    const int b  = blockIdx.z;
    const int l0 = blockIdx.x * 32, c0 = blockIdx.y * 32;
    const int lx = threadIdx.x, ly = threadIdx.y;
    const float* base = in + ((size_t)b * CC + c0) * LL + l0;
#pragma unroll
    for (int i = 0; i < 4; ++i) t[ly + i * 8][lx] = base[(size_t)(ly + i * 8) * LL + lx];
    __syncthreads();
    float* obase = outp + ((size_t)b * LL + l0) * CC + c0;
#pragma unroll
    for (int i = 0; i < 4; ++i) obase[(size_t)(ly + i * 8) * CC + lx] = t[lx][ly + i * 8];
}

// ---------------- main kernel ----------------
template <bool TPATH>
__global__ __launch_bounds__(NT) void informer_kernel(
    const float* __restrict__ xin,   // TPATH ? xT [B,C,L] : x [B,L,C]
    const float* __restrict__ gWq, const float* __restrict__ gbq,
    const float* __restrict__ gWk, const float* __restrict__ gbk,
    const float* __restrict__ gWv, const float* __restrict__ gbv,
    const float* __restrict__ gWo, const float* __restrict__ gbo,
    const float* __restrict__ gw1, const float* __restrict__ gb1,
    const float* __restrict__ gw2, const float* __restrict__ gb2,
    const float* __restrict__ gg1, const float* __restrict__ gbe1,
    const float* __restrict__ gg2, const float* __restrict__ gbe2,
    const int* __restrict__ idx,
    float* __restrict__ outp)        // TPATH ? outT [B,C,L] : out [B,L,C]
{
    const int tid  = threadIdx.x;
    const int lane = tid & 63;
    const int wid  = tid >> 6;
    const int blk  = blockIdx.x;     // b*CC + c
    const int b    = blk >> 7;
    const int c    = blk & (CC - 1);

    __shared__ float  s_xc[LL];
    __shared__ float  s_kc[LL];      // k (steps 1-5), then ctx/LN buffer (steps 6-7)
    __shared__ float  s_v[LL];
    __shared__ float  s_red[NW];
    __shared__ double s_cv[NW * UU];
    __shared__ int    s_ci[NW * UU];
    __shared__ int    s_top[UU];
    __shared__ float  s_upd[UU];

    const float Wq = *gWq, bq = *gbq, Wk = *gWk, bk = *gbk;
    const float Wv = *gWv, bv = *gbv, Wo = *gWo, bo = *gbo;
    const float w1 = *gw1, b1 = *gb1, w2 = *gw2, b2 = *gb2;
    const float g1 = *gg1, be1 = *gbe1, g2 = *gg2, be2 = *gbe2;

    const float* xrow;
    float* orow;
    size_t str;
    if (TPATH) {
        xrow = xin  + ((size_t)b * CC + c) * LL;
        orow = outp + ((size_t)b * CC + c) * LL;
        str = 1;
    } else {
        xrow = xin  + (size_t)b * LL * CC + c;
        orow = outp + (size_t)b * LL * CC + c;
        str = CC;
    }

    // ---- step 1: load x row, compute k,v; accumulate v-sum, k-min/max
    float vsum = 0.f, kmn = 3.4e38f, kmx = -3.4e38f;
    for (int l = tid; l < LL; l += NT) {
        float xv = xrow[(size_t)l * str];
        s_xc[l] = xv;
        float kv = __fadd_rn(__fmul_rn(xv, Wk), bk);
        float vv = __fadd_rn(__fmul_rn(xv, Wv), bv);
        s_kc[l] = kv;
        s_v[l] = vv;
        vsum += vv;
        kmn = fminf(kmn, kv);
        kmx = fmaxf(kmx, kv);
    }
    // barriers inside reducers make s_* visible
    const float vmean  = blockSum(vsum, s_red) * (1.f / (float)LL);
    const float kmxAll = blockMax(kmx, s_red);
    const float kmnAll = blockMin(kmn, s_red);

    // ---- step 2: M[l] = max_u(q*Ks) - q*sum_u(Ks)/L  (f64 for exact ordering)
    double mloc[8];  // element l = tid + 256*j
#pragma unroll
    for (int j = 0; j < 8; ++j) {
        const int l = tid + NT * j;
        const float qv = __fadd_rn(__fmul_rn(s_xc[l], Wq), bq);
        const double qd = (double)qv;
        const int* row = idx + l * UU;
        float kmaxs = -3.4e38f, kmins = 3.4e38f;
        double ssum = 0.0;
#pragma unroll 8
        for (int u = 0; u < UU; ++u) {
            float kv = s_kc[row[u]];
            kmaxs = fmaxf(kmaxs, kv);
            kmins = fminf(kmins, kv);
            ssum += (double)kv;
        }
        double qmax = (qd >= 0.0) ? qd * (double)kmaxs : qd * (double)kmins;
        mloc[j] = qmax - qd * ssum * (1.0 / (double)LL);
    }

    // ---- step 3a: per-wave top-40 via shuffles only (no block barriers)
    double wbv = mloc[0]; int wbi = tid;
#pragma unroll
    for (int j = 1; j < 8; ++j)
        if (mloc[j] > wbv) { wbv = mloc[j]; wbi = tid + NT * j; }

    for (int t = 0; t < UU; ++t) {
        double rv = wbv; int ri = wbi;
#pragma unroll
        for (int off = 1; off < 64; off <<= 1) {
            double ov = __shfl_xor(rv, off, 64);
            int    oi = __shfl_xor(ri, off, 64);
            if (ov > rv || (ov == rv && oi < ri)) { rv = ov; ri = oi; }
        }
        if (lane == 0) { s_cv[wid * UU + t] = rv; s_ci[wid * UU + t] = ri; }
        if (wbi == ri) {   // owner: invalidate + rescan
#pragma unroll
            for (int j = 0; j < 8; ++j) if ((tid + NT * j) == ri) mloc[j] = -1e300;
            wbv = mloc[0]; wbi = tid;
#pragma unroll
            for (int j = 1; j < 8; ++j)
                if (mloc[j] > wbv) { wbv = mloc[j]; wbi = tid + NT * j; }
        }
    }
    __syncthreads();

    // ---- step 3b: merge 4 sorted 40-lists -> global top-40 (wave 0 only)
    if (wid == 0) {
        double c0v = s_cv[lane],      c1v = s_cv[lane + 64];
        int    c0i = s_ci[lane],      c1i = s_ci[lane + 64];
        double c2v = (lane < 32) ? s_cv[lane + 128] : -1e300;
        int    c2i = (lane < 32) ? s_ci[lane + 128] : (LL + 1);
        for (int t = 0; t < UU; ++t) {
            double rv = c0v; int ri = c0i;
            if (c1v > rv || (c1v == rv && c1i < ri)) { rv = c1v; ri = c1i; }
            if (c2v > rv || (c2v == rv && c2i < ri)) { rv = c2v; ri = c2i; }
#pragma unroll
            for (int off = 1; off < 64; off <<= 1) {
                double ov = __shfl_xor(rv, off, 64);
                int    oi = __shfl_xor(ri, off, 64);
                if (ov > rv || (ov == rv && oi < ri)) { rv = ov; ri = oi; }
            }
            if (lane == 0) s_top[t] = ri;
            if (c0i == ri) c0v = -1e300;
            else if (c1i == ri) c1v = -1e300;
            else if (c2i == ri) c2v = -1e300;
        }
    }
    __syncthreads();

    // ---- step 4: upd[u] = softmax(q_p * k) . v — one u per wave, 10 rounds
    for (int r = 0; r < UU / NW; ++r) {
        const int u = r * NW + wid;
        const int p = s_top[u];
        const float qp = __fadd_rn(__fmul_rn(s_xc[p], Wq), bq);
        const float smax = (qp >= 0.f) ? qp * kmxAll : qp * kmnAll;
        float se = 0.f, sev = 0.f;
        for (int l = lane; l < LL; l += 64) {
            float e = __expf(qp * s_kc[l] - smax);
            se += e;
            sev = fmaf(e, s_v[l], sev);
        }
#pragma unroll
        for (int off = 1; off < 64; off <<= 1) {
            se  += __shfl_xor(se,  off, 64);
            sev += __shfl_xor(sev, off, 64);
        }
        if (lane == 0) s_upd[u] = sev / se;
    }
    __syncthreads();

    // ---- step 5: ctx (reuse s_kc: k is dead) = vmean, scatter upd
    for (int l = tid; l < LL; l += NT) s_kc[l] = vmean;
    __syncthreads();
    if (tid < UU) s_kc[s_top[tid]] = s_upd[tid];
    __syncthreads();

    // ---- step 6: t = xc + ctx*Wo + bo; LN1
    float lsum = 0.f;
    for (int l = tid; l < LL; l += NT) {
        float tv = s_xc[l] + __fadd_rn(__fmul_rn(s_kc[l], Wo), bo);
        s_kc[l] = tv;
        lsum += tv;
    }
    const float mean1 = blockSum(lsum, s_red) * (1.f / (float)LL);
    float lss = 0.f;
    for (int l = tid; l < LL; l += NT) { float d = s_kc[l] - mean1; lss += d * d; }
    const float var1 = blockSum(lss, s_red) * (1.f / (float)LL);
    const float rs1 = rsqrtf(var1 + EPSF);

    // ---- step 7: x1 -> gelu FFN -> z; LN2 -> out
    float lsum2 = 0.f;
    for (int l = tid; l < LL; l += NT) {
        float x1 = (s_kc[l] - mean1) * rs1 * g1 + be1;
        float a  = x1 * w1 + b1;
        float y  = 0.5f * a * (1.f + erff(a * 0.70710678118654752f));
        y = y * w2 + b2;
        float z = x1 + y;
        s_kc[l] = z;
        lsum2 += z;
    }
    const float mean2 = blockSum(lsum2, s_red) * (1.f / (float)LL);
    float lss2 = 0.f;
    for (int l = tid; l < LL; l += NT) { float d = s_kc[l] - mean2; lss2 += d * d; }
    const float var2 = blockSum(lss2, s_red) * (1.f / (float)LL);
    const float rs2 = rsqrtf(var2 + EPSF);

    for (int l = tid; l < LL; l += NT)
        orow[(size_t)l * str] = (s_kc[l] - mean2) * rs2 * g2 + be2;
}

extern "C" void kernel_launch(void* const* d_in, const int* in_sizes, int n_in,
                              void* d_out, int out_size, void* d_ws, size_t ws_size,
                              hipStream_t stream) {
    const float* x   = (const float*)d_in[0];
    const float* Wq  = (const float*)d_in[1];
    const float* bq  = (const float*)d_in[2];
    const float* Wk  = (const float*)d_in[3];
    const float* bk  = (const float*)d_in[4];
    const float* Wv  = (const float*)d_in[5];
    const float* bv  = (const float*)d_in[6];
    const float* Wo  = (const float*)d_in[7];
    const float* bo  = (const float*)d_in[8];
    const float* w1  = (const float*)d_in[9];
    const float* b1  = (const float*)d_in[10];
    const float* w2  = (const float*)d_in[11];
    const float* b2  = (const float*)d_in[12];
    const float* g1  = (const float*)d_in[13];
    const float* be1 = (const float*)d_in[14];
    const float* g2  = (const float*)d_in[15];
    const float* be2 = (const float*)d_in[16];
    const int*   idx = (const int*)d_in[17];
    float* out = (float*)d_out;

    const size_t SZ = (size_t)BB * LL * CC * sizeof(float);  // 16 MB

    if (ws_size >= 2 * SZ) {
        float* xT   = (float*)d_ws;
        float* outT = (float*)((char*)d_ws + SZ);
        transpose_in<<<dim3(CC / 32, LL / 32, BB), dim3(32, 8), 0, stream>>>(x, xT);
        informer_kernel<true><<<dim3(BB * CC), dim3(NT), 0, stream>>>(
            xT, Wq, bq, Wk, bk, Wv, bv, Wo, bo, w1, b1, w2, b2,
            g1, be1, g2, be2, idx, outT);
        transpose_out<<<dim3(LL / 32, CC / 32, BB), dim3(32, 8), 0, stream>>>(outT, out);
    } else {
        informer_kernel<false><<<dim3(BB * CC), dim3(NT), 0, stream>>>(
            x, Wq, bq, Wk, bk, Wv, bv, Wo, bo, w1, b1, w2, b2,
            g1, be1, g2, be2, idx, out);
    }
}

// Round 4
// 317.472 us; speedup vs baseline: 1.1500x; 1.1030x over previous
//
#include <hip/hip_runtime.h>
#include <math.h>

#define LL 2048
#define CC 128
#define BB 16
#define UU 40
#define NT 256
#define NW 4
#define EPSF 1e-5f

// ---------------- reduction helpers ----------------
__device__ __forceinline__ float waveSum(float v) {
#pragma unroll
    for (int off = 1; off < 64; off <<= 1) v += __shfl_xor(v, off, 64);
    return v;
}
__device__ __forceinline__ float waveMax(float v) {
#pragma unroll
    for (int off = 1; off < 64; off <<= 1) v = fmaxf(v, __shfl_xor(v, off, 64));
    return v;
}
__device__ __forceinline__ float waveMin(float v) {
#pragma unroll
    for (int off = 1; off < 64; off <<= 1) v = fminf(v, __shfl_xor(v, off, 64));
    return v;
}
__device__ __forceinline__ float blockSum(float v, volatile float* scr) {
    v = waveSum(v);
    const int lane = threadIdx.x & 63, wid = threadIdx.x >> 6;
    __syncthreads();
    if (lane == 0) scr[wid] = v;
    __syncthreads();
    return scr[0] + scr[1] + scr[2] + scr[3];
}

// ---------------- transpose kernels ----------------
__global__ __launch_bounds__(256) void transpose_in(const float* __restrict__ in,
                                                    float* __restrict__ outp) {
    __shared__ float t[32][33];
    const int b  = blockIdx.z;
    const int c0 = blockIdx.x * 32, l0 = blockIdx.y * 32;
    const int lx = threadIdx.x, ly = threadIdx.y;
    const float* base = in + ((size_t)b * LL + l0) * CC + c0;
#pragma unroll
    for (int i = 0; i < 4; ++i) t[ly + i * 8][lx] = base[(size_t)(ly + i * 8) * CC + lx];
    __syncthreads();
    float* obase = outp + ((size_t)b * CC + c0) * LL + l0;
#pragma unroll
    for (int i = 0; i < 4; ++i) obase[(size_t)(ly + i * 8) * LL + lx] = t[lx][ly + i * 8];
}
__global__ __launch_bounds__(256) void transpose_out(const float* __restrict__ in,
                                                     float* __restrict__ outp) {
    __shared__ float t[32][33];
    const int b  = blockIdx.z;
    const int l0 = blockIdx.x * 32, c0 = blockIdx.y * 32;
    const int lx = threadIdx.x, ly = threadIdx.y;
    const float* base = in + ((size_t)b * CC + c0) * LL + l0;
#pragma unroll
    for (int i = 0; i < 4; ++i) t[ly + i * 8][lx] = base[(size_t)(ly + i * 8) * LL + lx];
    __syncthreads();
    float* obase = outp + ((size_t)b * LL + l0) * CC + c0;
#pragma unroll
    for (int i = 0; i < 4; ++i) obase[(size_t)(ly + i * 8) * CC + lx] = t[lx][ly + i * 8];
}

// ---------------- M aggregate kernel ----------------
// Computes M[b,l,c] for all c at once using coalesced row gathers of x[B,L,C].
// k = Wk*x+bk is monotone affine => max/min/sum of k over sampled set derive
// from max/min/sum of x. Rounding mirrors jax: max-term = f32(q * f32(Wk*xext+bk))
// bit-exact; sum-term in f64 (negligible deviation, /2048); final f32 subtract.
__global__ __launch_bounds__(256) void agg_kernel(
    const float* __restrict__ x, const int* __restrict__ idx,
    const float* __restrict__ gWq, const float* __restrict__ gbq,
    const float* __restrict__ gWk, const float* __restrict__ gbk,
    float* __restrict__ M)
{
    __shared__ int s_idx[8 * UU];
    const int tid = threadIdx.x;
    const int b   = blockIdx.y;
    const int l0  = blockIdx.x * 8;
    if (tid < 256)      s_idx[tid]       = idx[l0 * UU + tid];
    if (tid < 8 * UU - 256) s_idx[256 + tid] = idx[l0 * UU + 256 + tid];
    __syncthreads();

    const int s = tid & 31;       // c-quad: c = 4s..4s+3
    const int r = tid >> 5;       // row slot
    const int l = l0 + r;
    const float Wq = *gWq, bq = *gbq, Wk = *gWk, bk = *gbk;

    const float4* xb = (const float4*)(x + (size_t)b * LL * CC);
    float4 xo4 = xb[(size_t)l * 32 + s];
    float xo[4] = {xo4.x, xo4.y, xo4.z, xo4.w};

    float  mx[4] = {-3.4e38f, -3.4e38f, -3.4e38f, -3.4e38f};
    float  mn[4] = { 3.4e38f,  3.4e38f,  3.4e38f,  3.4e38f};
    double sm[4] = {0.0, 0.0, 0.0, 0.0};
    const int* rowp = &s_idx[r * UU];
#pragma unroll 8
    for (int u = 0; u < UU; ++u) {
        const int i = rowp[u];
        float4 xv = xb[(size_t)i * 32 + s];
        float xa[4] = {xv.x, xv.y, xv.z, xv.w};
#pragma unroll
        for (int t = 0; t < 4; ++t) {
            mx[t] = fmaxf(mx[t], xa[t]);
            mn[t] = fminf(mn[t], xa[t]);
            sm[t] += (double)xa[t];
        }
    }
    float mo[4];
#pragma unroll
    for (int t = 0; t < 4; ++t) {
        const float xH = (Wk >= 0.f) ? mx[t] : mn[t];
        const float xL = (Wk >= 0.f) ? mn[t] : mx[t];
        const float kH = __fadd_rn(__fmul_rn(xH, Wk), bk);   // = max_u k, bit-exact
        const float kL = __fadd_rn(__fmul_rn(xL, Wk), bk);   // = min_u k, bit-exact
        const float q  = __fadd_rn(__fmul_rn(xo[t], Wq), bq);
        const float t1 = __fmul_rn(q, (q >= 0.f) ? kH : kL); // = max_u f32(q*k_u)
        const double ks = (double)Wk * sm[t] + 40.0 * (double)bk;
        const float t2 = (float)(((double)q * ks) * (1.0 / 2048.0));
        mo[t] = __fsub_rn(t1, t2);
    }
    float4 Mo = make_float4(mo[0], mo[1], mo[2], mo[3]);
    ((float4*)(M + ((size_t)b * LL + l) * CC))[s] = Mo;
}

// ---------------- main kernel (transposed path, M precomputed) ----------------
__global__ __launch_bounds__(NT) void informer_main(
    const float* __restrict__ xT,    // [B,C,L]
    const float* __restrict__ Mg,    // [B,L,C] f32 (stored in d_out)
    const float* __restrict__ gWq, const float* __restrict__ gbq,
    const float* __restrict__ gWk, const float* __restrict__ gbk,
    const float* __restrict__ gWv, const float* __restrict__ gbv,
    const float* __restrict__ gWo, const float* __restrict__ gbo,
    const float* __restrict__ gw1, const float* __restrict__ gb1,
    const float* __restrict__ gw2, const float* __restrict__ gb2,
    const float* __restrict__ gg1, const float* __restrict__ gbe1,
    const float* __restrict__ gg2, const float* __restrict__ gbe2,
    float* __restrict__ outT)        // [B,C,L]
{
    const int tid = threadIdx.x;
    const int ln  = tid & 63;
    const int wid = tid >> 6;
    const int blk = blockIdx.x;      // b*CC + c
    const int b   = blk >> 7;
    const int c   = blk & (CC - 1);

    __shared__ __align__(16) float s_xc[LL];
    __shared__ __align__(16) float s_wk[LL];
    __shared__ float s_red[NW];
    __shared__ float s_cv[NW * UU];
    __shared__ int   s_ci[NW * UU];
    __shared__ int   s_top[UU];
    __shared__ float s_upd[UU];

    const float Wq = *gWq, bq = *gbq, Wk = *gWk, bk = *gbk;
    const float Wv = *gWv, bv = *gbv, Wo = *gWo, bo = *gbo;
    const float w1 = *gw1, b1 = *gb1, w2 = *gw2, b2 = *gb2;
    const float g1 = *gg1, be1 = *gbe1, g2 = *gg2, be2 = *gbe2;

    const float4* xrow4 = (const float4*)(xT + ((size_t)b * CC + c) * LL);
    float4* orow4 = (float4*)(outT + ((size_t)b * CC + c) * LL);
    float4* s_xc4 = (float4*)s_xc;
    float4* s_wk4 = (float4*)s_wk;

    // ---- step 1: each wave loads the FULL row into registers (k,v), wave-local reductions
    float4 kv[8], vv[8];
    float vsum = 0.f, kmn = 3.4e38f, kmx = -3.4e38f;
#pragma unroll
    for (int m = 0; m < 8; ++m) {
        float4 xv = xrow4[ln + m * 64];
        if (wid == 0) s_xc4[ln + m * 64] = xv;
        float4 kk, vx;
        kk.x = __fadd_rn(__fmul_rn(xv.x, Wk), bk);
        kk.y = __fadd_rn(__fmul_rn(xv.y, Wk), bk);
        kk.z = __fadd_rn(__fmul_rn(xv.z, Wk), bk);
        kk.w = __fadd_rn(__fmul_rn(xv.w, Wk), bk);
        vx.x = __fadd_rn(__fmul_rn(xv.x, Wv), bv);
        vx.y = __fadd_rn(__fmul_rn(xv.y, Wv), bv);
        vx.z = __fadd_rn(__fmul_rn(xv.z, Wv), bv);
        vx.w = __fadd_rn(__fmul_rn(xv.w, Wv), bv);
        kv[m] = kk; vv[m] = vx;
        vsum += vx.x + vx.y + vx.z + vx.w;
        kmx = fmaxf(kmx, fmaxf(fmaxf(kk.x, kk.y), fmaxf(kk.z, kk.w)));
        kmn = fminf(kmn, fminf(fminf(kk.x, kk.y), fminf(kk.z, kk.w)));
    }
    vsum = waveSum(vsum);
    kmx  = waveMax(kmx);
    kmn  = waveMin(kmn);
    const float vmean = vsum * (1.f / (float)LL);

    // ---- step 2: per-wave top-40 over its 512-element range (M from global, f32)
    const int lbase = wid * 512 + ln;
    const float* Mrow = Mg + (size_t)b * LL * CC + c;
    float mloc[8];
#pragma unroll
    for (int j = 0; j < 8; ++j) mloc[j] = Mrow[(size_t)(lbase + 64 * j) * CC];

    float wbv = mloc[0]; int wbi = lbase;
#pragma unroll
    for (int j = 1; j < 8; ++j)
        if (mloc[j] > wbv) { wbv = mloc[j]; wbi = lbase + 64 * j; }

    for (int t = 0; t < UU; ++t) {
        float rv = wbv; int ri = wbi;
#pragma unroll
        for (int off = 1; off < 64; off <<= 1) {
            float ov = __shfl_xor(rv, off, 64);
            int   oi = __shfl_xor(ri, off, 64);
            if (ov > rv || (ov == rv && oi < ri)) { rv = ov; ri = oi; }
        }
        if (ln == 0) { s_cv[wid * UU + t] = rv; s_ci[wid * UU + t] = ri; }
        if (wbi == ri) {   // owner: invalidate + rescan
#pragma unroll
            for (int j = 0; j < 8; ++j) if (lbase + 64 * j == ri) mloc[j] = -3.4e38f;
            wbv = mloc[0]; wbi = lbase;
#pragma unroll
            for (int j = 1; j < 8; ++j)
                if (mloc[j] > wbv) { wbv = mloc[j]; wbi = lbase + 64 * j; }
        }
    }
    __syncthreads();

    // ---- step 3: merge 4x40 candidates -> global top-40 (wave 0; lanes cover all 160 slots)
    if (wid == 0) {
        float c0v = s_cv[ln],      c1v = s_cv[ln + 64];
        int   c0i = s_ci[ln],      c1i = s_ci[ln + 64];
        float c2v = (ln < 32) ? s_cv[ln + 128] : -3.4e38f;
        int   c2i = (ln < 32) ? s_ci[ln + 128] : (LL + 1);
        for (int t = 0; t < UU; ++t) {
            float rv = c0v; int ri = c0i;
            if (c1v > rv || (c1v == rv && c1i < ri)) { rv = c1v; ri = c1i; }
            if (c2v > rv || (c2v == rv && c2i < ri)) { rv = c2v; ri = c2i; }
#pragma unroll
            for (int off = 1; off < 64; off <<= 1) {
                float ov = __shfl_xor(rv, off, 64);
                int   oi = __shfl_xor(ri, off, 64);
                if (ov > rv || (ov == rv && oi < ri)) { rv = ov; ri = oi; }
            }
            if (ln == 0) s_top[t] = ri;
            if (c0i == ri) c0v = -3.4e38f;
            else if (c1i == ri) c1v = -3.4e38f;
            else if (c2i == ri) c2v = -3.4e38f;
        }
    }
    __syncthreads();

    // ---- step 4: upd[u] = softmax(q_p * k) . v — registers only, one u per wave
    for (int r = 0; r < UU / NW; ++r) {
        const int u = r * NW + wid;
        const int p = s_top[u];
        const float qp = __fadd_rn(__fmul_rn(s_xc[p], Wq), bq);
        const float smax = (qp >= 0.f) ? __fmul_rn(qp, kmx) : __fmul_rn(qp, kmn);
        float se = 0.f, sev = 0.f;
#pragma unroll
        for (int m = 0; m < 8; ++m) {
            float4 kk = kv[m], vx = vv[m];
            float e0 = __expf(qp * kk.x - smax);
            float e1 = __expf(qp * kk.y - smax);
            float e2 = __expf(qp * kk.z - smax);
            float e3 = __expf(qp * kk.w - smax);
            se += e0 + e1 + e2 + e3;
            sev = fmaf(e0, vx.x, fmaf(e1, vx.y, fmaf(e2, vx.z, fmaf(e3, vx.w, sev))));
        }
        se  = waveSum(se);
        sev = waveSum(sev);
        if (ln == 0) s_upd[u] = sev / se;
    }
    __syncthreads();

    // ---- step 5: ctx = vmean, scatter upd
#pragma unroll
    for (int m = 0; m < 2; ++m)
        s_wk4[tid + m * 256] = make_float4(vmean, vmean, vmean, vmean);
    __syncthreads();
    if (tid < UU) s_wk[s_top[tid]] = s_upd[tid];
    __syncthreads();

    // ---- step 6: t = xc + ctx*Wo + bo; LN1
    float lsum = 0.f;
#pragma unroll
    for (int m = 0; m < 2; ++m) {
        const int f = tid + m * 256;
        float4 cx = s_wk4[f], xc = s_xc4[f], tv;
        tv.x = xc.x + __fadd_rn(__fmul_rn(cx.x, Wo), bo);
        tv.y = xc.y + __fadd_rn(__fmul_rn(cx.y, Wo), bo);
        tv.z = xc.z + __fadd_rn(__fmul_rn(cx.z, Wo), bo);
        tv.w = xc.w + __fadd_rn(__fmul_rn(cx.w, Wo), bo);
        s_wk4[f] = tv;
        lsum += tv.x + tv.y + tv.z + tv.w;
    }
    const float mean1 = blockSum(lsum, s_red) * (1.f / (float)LL);
    float lss = 0.f;
#pragma unroll
    for (int m = 0; m < 2; ++m) {
        float4 tv = s_wk4[tid + m * 256];
        float d0 = tv.x - mean1, d1 = tv.y - mean1, d2 = tv.z - mean1, d3 = tv.w - mean1;
        lss += d0 * d0 + d1 * d1 + d2 * d2 + d3 * d3;
    }
    const float var1 = blockSum(lss, s_red) * (1.f / (float)LL);
    const float rs1 = rsqrtf(var1 + EPSF);

    // ---- step 7: x1 -> gelu FFN -> z; LN2 -> out
    float lsum2 = 0.f;
#pragma unroll
    for (int m = 0; m < 2; ++m) {
        const int f = tid + m * 256;
        float4 tv = s_wk4[f], zz;
        {
            float x1 = (tv.x - mean1) * rs1 * g1 + be1;
            float a = x1 * w1 + b1;
            float y = 0.5f * a * (1.f + erff(a * 0.70710678118654752f));
            zz.x = x1 + (y * w2 + b2);
        }
        {
            float x1 = (tv.y - mean1) * rs1 * g1 + be1;
            float a = x1 * w1 + b1;
            float y = 0.5f * a * (1.f + erff(a * 0.70710678118654752f));
            zz.y = x1 + (y * w2 + b2);
        }
        {
            float x1 = (tv.z - mean1) * rs1 * g1 + be1;
            float a = x1 * w1 + b1;
            float y = 0.5f * a * (1.f + erff(a * 0.70710678118654752f));
            zz.z = x1 + (y * w2 + b2);
        }
        {
            float x1 = (tv.w - mean1) * rs1 * g1 + be1;
            float a = x1 * w1 + b1;
            float y = 0.5f * a * (1.f + erff(a * 0.70710678118654752f));
            zz.w = x1 + (y * w2 + b2);
        }
        s_wk4[f] = zz;
        lsum2 += zz.x + zz.y + zz.z + zz.w;
    }
    const float mean2 = blockSum(lsum2, s_red) * (1.f / (float)LL);
    float lss2 = 0.f;
#pragma unroll
    for (int m = 0; m < 2; ++m) {
        float4 zz = s_wk4[tid + m * 256];
        float d0 = zz.x - mean2, d1 = zz.y - mean2, d2 = zz.z - mean2, d3 = zz.w - mean2;
        lss2 += d0 * d0 + d1 * d1 + d2 * d2 + d3 * d3;
    }
    const float var2 = blockSum(lss2, s_red) * (1.f / (float)LL);
    const float rs2 = rsqrtf(var2 + EPSF);

#pragma unroll
    for (int m = 0; m < 2; ++m) {
        const int f = tid + m * 256;
        float4 zz = s_wk4[f], oo;
        oo.x = (zz.x - mean2) * rs2 * g2 + be2;
        oo.y = (zz.y - mean2) * rs2 * g2 + be2;
        oo.z = (zz.z - mean2) * rs2 * g2 + be2;
        oo.w = (zz.w - mean2) * rs2 * g2 + be2;
        orow4[f] = oo;
    }
}

// ---------------- fallback (strided, self-contained; only if ws too small) ----------------
__global__ __launch_bounds__(NT) void informer_fallback(
    const float* __restrict__ xin,
    const float* __restrict__ gWq, const float* __restrict__ gbq,
    const float* __restrict__ gWk, const float* __restrict__ gbk,
    const float* __restrict__ gWv, const float* __restrict__ gbv,
    const float* __restrict__ gWo, const float* __restrict__ gbo,
    const float* __restrict__ gw1, const float* __restrict__ gb1,
    const float* __restrict__ gw2, const float* __restrict__ gb2,
    const float* __restrict__ gg1, const float* __restrict__ gbe1,
    const float* __restrict__ gg2, const float* __restrict__ gbe2,
    const int* __restrict__ idx,
    float* __restrict__ outp)
{
    const int tid  = threadIdx.x;
    const int lane = tid & 63;
    const int wid  = tid >> 6;
    const int blk  = blockIdx.x;
    const int b    = blk >> 7;
    const int c    = blk & (CC - 1);

    __shared__ float  s_xc[LL];
    __shared__ float  s_kc[LL];
    __shared__ float  s_v[LL];
    __shared__ float  s_red[NW];
    __shared__ double s_cv[NW * UU];
    __shared__ int    s_ci[NW * UU];
    __shared__ int    s_top[UU];
    __shared__ float  s_upd[UU];

    const float Wq = *gWq, bq = *gbq, Wk = *gWk, bk = *gbk;
    const float Wv = *gWv, bv = *gbv, Wo = *gWo, bo = *gbo;
    const float w1 = *gw1, b1 = *gb1, w2 = *gw2, b2 = *gb2;
    const float g1 = *gg1, be1 = *gbe1, g2 = *gg2, be2 = *gbe2;

    const float* xrow = xin + (size_t)b * LL * CC + c;
    float* orow = outp + (size_t)b * LL * CC + c;

    float vsum = 0.f, kmn = 3.4e38f, kmx = -3.4e38f;
    for (int l = tid; l < LL; l += NT) {
        float xv = xrow[(size_t)l * CC];
        s_xc[l] = xv;
        float kvv = __fadd_rn(__fmul_rn(xv, Wk), bk);
        float vvv = __fadd_rn(__fmul_rn(xv, Wv), bv);
        s_kc[l] = kvv;
        s_v[l] = vvv;
        vsum += vvv;
        kmn = fminf(kmn, kvv);
        kmx = fmaxf(kmx, kvv);
    }
    const float vmean  = blockSum(vsum, s_red) * (1.f / (float)LL);
    float t1 = waveMax(kmx);
    __syncthreads();
    if (lane == 0) s_red[wid] = t1;
    __syncthreads();
    const float kmxAll = fmaxf(fmaxf(s_red[0], s_red[1]), fmaxf(s_red[2], s_red[3]));
    float t2 = waveMin(kmn);
    __syncthreads();
    if (lane == 0) s_red[wid] = t2;
    __syncthreads();
    const float kmnAll = fminf(fminf(s_red[0], s_red[1]), fminf(s_red[2], s_red[3]));

    double mloc[8];
#pragma unroll
    for (int j = 0; j < 8; ++j) {
        const int l = tid + NT * j;
        const float qv = __fadd_rn(__fmul_rn(s_xc[l], Wq), bq);
        const double qd = (double)qv;
        const int* row = idx + l * UU;
        float kmaxs = -3.4e38f, kmins = 3.4e38f;
        double ssum = 0.0;
#pragma unroll 8
        for (int u = 0; u < UU; ++u) {
            float kvv = s_kc[row[u]];
            kmaxs = fmaxf(kmaxs, kvv);
            kmins = fminf(kmins, kvv);
            ssum += (double)kvv;
        }
        double qmax = (qd >= 0.0) ? qd * (double)kmaxs : qd * (double)kmins;
        mloc[j] = qmax - qd * ssum * (1.0 / (double)LL);
    }

    double wbv = mloc[0]; int wbi = tid;
#pragma unroll
    for (int j = 1; j < 8; ++j)
        if (mloc[j] > wbv) { wbv = mloc[j]; wbi = tid + NT * j; }

    for (int t = 0; t < UU; ++t) {
        double rv = wbv; int ri = wbi;
#pragma unroll
        for (int off = 1; off < 64; off <<= 1) {
            double ov = __shfl_xor(rv, off, 64);
            int    oi = __shfl_xor(ri, off, 64);
            if (ov > rv || (ov == rv && oi < ri)) { rv = ov; ri = oi; }
        }
        if (lane == 0) { s_cv[wid * UU + t] = rv; s_ci[wid * UU + t] = ri; }
        if (wbi == ri) {
#pragma unroll
            for (int j = 0; j < 8; ++j) if ((tid + NT * j) == ri) mloc[j] = -1e300;
            wbv = mloc[0]; wbi = tid;
#pragma unroll
            for (int j = 1; j < 8; ++j)
                if (mloc[j] > wbv) { wbv = mloc[j]; wbi = tid + NT * j; }
        }
    }
    __syncthreads();

    if (wid == 0) {
        double c0v = s_cv[lane], c1v = s_cv[lane + 64];
        int    c0i = s_ci[lane], c1i = s_ci[lane + 64];
        double c2v = (lane < 32) ? s_cv[lane + 128] : -1e300;
        int    c2i = (lane < 32) ? s_ci[lane + 128] : (LL + 1);
        for (int t = 0; t < UU; ++t) {
            double rv = c0v; int ri = c0i;
            if (c1v > rv || (c1v == rv && c1i < ri)) { rv = c1v; ri = c1i; }
            if (c2v > rv || (c2v == rv && c2i < ri)) { rv = c2v; ri = c2i; }
#pragma unroll
            for (int off = 1; off < 64; off <<= 1) {
                double ov = __shfl_xor(rv, off, 64);
                int    oi = __shfl_xor(ri, off, 64);
                if (ov > rv || (ov == rv && oi < ri)) { rv = ov; ri = oi; }
            }
            if (lane == 0) s_top[t] = ri;
            if (c0i == ri) c0v = -1e300;
            else if (c1i == ri) c1v = -1e300;
            else if (c2i == ri) c2v = -1e300;
        }
    }
    __syncthreads();

    for (int r = 0; r < UU / NW; ++r) {
        const int u = r * NW + wid;
        const int p = s_top[u];
        const float qp = __fadd_rn(__fmul_rn(s_xc[p], Wq), bq);
        const float smax = (qp >= 0.f) ? qp * kmxAll : qp * kmnAll;
        float se = 0.f, sev = 0.f;
        for (int l = lane; l < LL; l += 64) {
            float e = __expf(qp * s_kc[l] - smax);
            se += e;
            sev = fmaf(e, s_v[l], sev);
        }
        se = waveSum(se); sev = waveSum(sev);
        if (lane == 0) s_upd[u] = sev / se;
    }
    __syncthreads();

    for (int l = tid; l < LL; l += NT) s_kc[l] = vmean;
    __syncthreads();
    if (tid < UU) s_kc[s_top[tid]] = s_upd[tid];
    __syncthreads();

    float lsum = 0.f;
    for (int l = tid; l < LL; l += NT) {
        float tv = s_xc[l] + __fadd_rn(__fmul_rn(s_kc[l], Wo), bo);
        s_kc[l] = tv;
        lsum += tv;
    }
    const float mean1 = blockSum(lsum, s_red) * (1.f / (float)LL);
    float lss = 0.f;
    for (int l = tid; l < LL; l += NT) { float d = s_kc[l] - mean1; lss += d * d; }
    const float var1 = blockSum(lss, s_red) * (1.f / (float)LL);
    const float rs1 = rsqrtf(var1 + EPSF);

    float lsum2 = 0.f;
    for (int l = tid; l < LL; l += NT) {
        float x1 = (s_kc[l] - mean1) * rs1 * g1 + be1;
        float a  = x1 * w1 + b1;
        float y  = 0.5f * a * (1.f + erff(a * 0.70710678118654752f));
        y = y * w2 + b2;
        float z = x1 + y;
        s_kc[l] = z;
        lsum2 += z;
    }
    const float mean2 = blockSum(lsum2, s_red) * (1.f / (float)LL);
    float lss2 = 0.f;
    for (int l = tid; l < LL; l += NT) { float d = s_kc[l] - mean2; lss2 += d * d; }
    const float var2 = blockSum(lss2, s_red) * (1.f / (float)LL);
    const float rs2 = rsqrtf(var2 + EPSF);

    for (int l = tid; l < LL; l += NT)
        orow[(size_t)l * CC] = (s_kc[l] - mean2) * rs2 * g2 + be2;
}

extern "C" void kernel_launch(void* const* d_in, const int* in_sizes, int n_in,
                              void* d_out, int out_size, void* d_ws, size_t ws_size,
                              hipStream_t stream) {
    const float* x   = (const float*)d_in[0];
    const float* Wq  = (const float*)d_in[1];
    const float* bq  = (const float*)d_in[2];
    const float* Wk  = (const float*)d_in[3];
    const float* bk  = (const float*)d_in[4];
    const float* Wv  = (const float*)d_in[5];
    const float* bv  = (const float*)d_in[6];
    const float* Wo  = (const float*)d_in[7];
    const float* bo  = (const float*)d_in[8];
    const float* w1  = (const float*)d_in[9];
    const float* b1  = (const float*)d_in[10];
    const float* w2  = (const float*)d_in[11];
    const float* b2  = (const float*)d_in[12];
    const float* g1  = (const float*)d_in[13];
    const float* be1 = (const float*)d_in[14];
    const float* g2  = (const float*)d_in[15];
    const float* be2 = (const float*)d_in[16];
    const int*   idx = (const int*)d_in[17];
    float* out = (float*)d_out;

    const size_t SZ = (size_t)BB * LL * CC * sizeof(float);  // 16 MB

    if (ws_size >= 2 * SZ) {
        float* xT   = (float*)d_ws;
        float* outT = (float*)((char*)d_ws + SZ);
        // M lives in d_out until transpose_out overwrites it at the end.
        agg_kernel<<<dim3(LL / 8, BB), dim3(256), 0, stream>>>(x, idx, Wq, bq, Wk, bk, out);
        transpose_in<<<dim3(CC / 32, LL / 32, BB), dim3(32, 8), 0, stream>>>(x, xT);
        informer_main<<<dim3(BB * CC), dim3(NT), 0, stream>>>(
            xT, out, Wq, bq, Wk, bk, Wv, bv, Wo, bo, w1, b1, w2, b2,
            g1, be1, g2, be2, outT);
        transpose_out<<<dim3(LL / 32, CC / 32, BB), dim3(32, 8), 0, stream>>>(outT, out);
    } else {
        informer_fallback<<<dim3(BB * CC), dim3(NT), 0, stream>>>(
            x, Wq, bq, Wk, bk, Wv, bv, Wo, bo, w1, b1, w2, b2,
            g1, be1, g2, be2, idx, out);
    }
}

// Round 5
// 292.809 us; speedup vs baseline: 1.2468x; 1.0842x over previous
//
#include <hip/hip_runtime.h>
#include <math.h>

#define LL 2048
#define CC 128
#define BB 16
#define UU 40
#define NT 256
#define NW 4
#define EPSF 1e-5f

// ---------------- reduction helpers ----------------
__device__ __forceinline__ float waveSum(float v) {
#pragma unroll
    for (int off = 1; off < 64; off <<= 1) v += __shfl_xor(v, off, 64);
    return v;
}
__device__ __forceinline__ float waveMax(float v) {
#pragma unroll
    for (int off = 1; off < 64; off <<= 1) v = fmaxf(v, __shfl_xor(v, off, 64));
    return v;
}
__device__ __forceinline__ float waveMin(float v) {
#pragma unroll
    for (int off = 1; off < 64; off <<= 1) v = fminf(v, __shfl_xor(v, off, 64));
    return v;
}
__device__ __forceinline__ float blockSum(float v, volatile float* scr) {
    v = waveSum(v);
    const int lane = threadIdx.x & 63, wid = threadIdx.x >> 6;
    __syncthreads();
    if (lane == 0) scr[wid] = v;
    __syncthreads();
    return scr[0] + scr[1] + scr[2] + scr[3];
}

// ---------------- transpose kernels ----------------
// dual: z<16 -> x[B,L,C]->xT[B,C,L] ; z>=16 -> M[B,L,C]->MT[B,C,L]
__global__ __launch_bounds__(256) void transpose_dual(
    const float* __restrict__ x,  float* __restrict__ xT,
    const float* __restrict__ M,  float* __restrict__ MT) {
    __shared__ float t[32][33];
    const int z  = blockIdx.z;
    const int b  = (z < BB) ? z : (z - BB);
    const float* in  = (z < BB) ? x  : M;
    float* outp      = (z < BB) ? xT : MT;
    const int c0 = blockIdx.x * 32, l0 = blockIdx.y * 32;
    const int lx = threadIdx.x, ly = threadIdx.y;
    const float* base = in + ((size_t)b * LL + l0) * CC + c0;
#pragma unroll
    for (int i = 0; i < 4; ++i) t[ly + i * 8][lx] = base[(size_t)(ly + i * 8) * CC + lx];
    __syncthreads();
    float* obase = outp + ((size_t)b * CC + c0) * LL + l0;
#pragma unroll
    for (int i = 0; i < 4; ++i) obase[(size_t)(ly + i * 8) * LL + lx] = t[lx][ly + i * 8];
}
__global__ __launch_bounds__(256) void transpose_out(const float* __restrict__ in,
                                                     float* __restrict__ outp) {
    __shared__ float t[32][33];
    const int b  = blockIdx.z;
    const int l0 = blockIdx.x * 32, c0 = blockIdx.y * 32;
    const int lx = threadIdx.x, ly = threadIdx.y;
    const float* base = in + ((size_t)b * CC + c0) * LL + l0;
#pragma unroll
    for (int i = 0; i < 4; ++i) t[ly + i * 8][lx] = base[(size_t)(ly + i * 8) * LL + lx];
    __syncthreads();
    float* obase = outp + ((size_t)b * LL + l0) * CC + c0;
#pragma unroll
    for (int i = 0; i < 4; ++i) obase[(size_t)(ly + i * 8) * CC + lx] = t[lx][ly + i * 8];
}

// ---------------- M aggregate kernel ----------------
// XCD-swizzled: linear block id g -> b = ((g&7)<<1)|((g>>3)&1), l0 = (g>>4)*8.
// Round-robin XCD assignment (g%8) then pins 2 batches per XCD -> 2 MB x
// working set per XCD L2 (4 MB) -> gathers become L2 hits instead of L3.
__global__ __launch_bounds__(256) void agg_kernel(
    const float* __restrict__ x, const int* __restrict__ idx,
    const float* __restrict__ gWq, const float* __restrict__ gbq,
    const float* __restrict__ gWk, const float* __restrict__ gbk,
    float* __restrict__ M)
{
    __shared__ int s_idx[8 * UU];
    const int tid = threadIdx.x;
    const int g   = blockIdx.x;
    const int b   = ((g & 7) << 1) | ((g >> 3) & 1);
    const int l0  = (g >> 4) * 8;
    if (tid < 256)          s_idx[tid]       = idx[l0 * UU + tid];
    if (tid < 8 * UU - 256) s_idx[256 + tid] = idx[l0 * UU + 256 + tid];
    __syncthreads();

    const int s = tid & 31;       // c-quad: c = 4s..4s+3
    const int r = tid >> 5;       // row slot
    const int l = l0 + r;
    const float Wq = *gWq, bq = *gbq, Wk = *gWk, bk = *gbk;

    const float4* xb = (const float4*)(x + (size_t)b * LL * CC);
    float4 xo4 = xb[(size_t)l * 32 + s];
    float xo[4] = {xo4.x, xo4.y, xo4.z, xo4.w};

    float  mx[4] = {-3.4e38f, -3.4e38f, -3.4e38f, -3.4e38f};
    float  mn[4] = { 3.4e38f,  3.4e38f,  3.4e38f,  3.4e38f};
    double sm[4] = {0.0, 0.0, 0.0, 0.0};
    const int* rowp = &s_idx[r * UU];
#pragma unroll 8
    for (int u = 0; u < UU; ++u) {
        const int i = rowp[u];
        float4 xv = xb[(size_t)i * 32 + s];
        float xa[4] = {xv.x, xv.y, xv.z, xv.w};
#pragma unroll
        for (int t = 0; t < 4; ++t) {
            mx[t] = fmaxf(mx[t], xa[t]);
            mn[t] = fminf(mn[t], xa[t]);
            sm[t] += (double)xa[t];
        }
    }
    float mo[4];
#pragma unroll
    for (int t = 0; t < 4; ++t) {
        const float xH = (Wk >= 0.f) ? mx[t] : mn[t];
        const float xL = (Wk >= 0.f) ? mn[t] : mx[t];
        const float kH = __fadd_rn(__fmul_rn(xH, Wk), bk);   // = max_u k, bit-exact
        const float kL = __fadd_rn(__fmul_rn(xL, Wk), bk);   // = min_u k, bit-exact
        const float q  = __fadd_rn(__fmul_rn(xo[t], Wq), bq);
        const float t1 = __fmul_rn(q, (q >= 0.f) ? kH : kL); // = max_u f32(q*k_u)
        const double ks = (double)Wk * sm[t] + 40.0 * (double)bk;
        const float t2 = (float)(((double)q * ks) * (1.0 / 2048.0));
        mo[t] = __fsub_rn(t1, t2);
    }
    float4 Mo = make_float4(mo[0], mo[1], mo[2], mo[3]);
    ((float4*)(M + ((size_t)b * LL + l) * CC))[s] = Mo;
}

// ---------------- main kernel (transposed path, MT coalesced) ----------------
// MoT: [B,C,L] — holds MT on entry; each block overwrites ITS OWN row with the
// output at the end (reads complete before writes, rows are block-exclusive).
__global__ __launch_bounds__(NT) void informer_main(
    const float* __restrict__ xT,    // [B,C,L]
    float* MoT,                      // [B,C,L] (no restrict: read M, write out)
    const float* __restrict__ gWq, const float* __restrict__ gbq,
    const float* __restrict__ gWk, const float* __restrict__ gbk,
    const float* __restrict__ gWv, const float* __restrict__ gbv,
    const float* __restrict__ gWo, const float* __restrict__ gbo,
    const float* __restrict__ gw1, const float* __restrict__ gb1,
    const float* __restrict__ gw2, const float* __restrict__ gb2,
    const float* __restrict__ gg1, const float* __restrict__ gbe1,
    const float* __restrict__ gg2, const float* __restrict__ gbe2)
{
    const int tid = threadIdx.x;
    const int ln  = tid & 63;
    const int wid = tid >> 6;
    const int blk = blockIdx.x;      // b*CC + c
    const int b   = blk >> 7;
    const int c   = blk & (CC - 1);

    __shared__ __align__(16) float s_xc[LL];
    __shared__ __align__(16) float s_wk[LL];
    __shared__ float s_red[NW];
    __shared__ float s_cv[NW * UU];
    __shared__ int   s_ci[NW * UU];
    __shared__ int   s_top[UU];
    __shared__ float s_upd[UU];

    const float Wq = *gWq, bq = *gbq, Wk = *gWk, bk = *gbk;
    const float Wv = *gWv, bv = *gbv, Wo = *gWo, bo = *gbo;
    const float w1 = *gw1, b1 = *gb1, w2 = *gw2, b2 = *gb2;
    const float g1 = *gg1, be1 = *gbe1, g2 = *gg2, be2 = *gbe2;

    const float4* xrow4 = (const float4*)(xT + ((size_t)b * CC + c) * LL);
    float* Mrow = MoT + ((size_t)b * CC + c) * LL;
    float4* orow4 = (float4*)Mrow;
    float4* s_xc4 = (float4*)s_xc;
    float4* s_wk4 = (float4*)s_wk;

    // ---- step 1: each wave loads the FULL row into registers (k,v), wave-local reductions
    float4 kv[8], vv[8];
    float vsum = 0.f, kmn = 3.4e38f, kmx = -3.4e38f;
#pragma unroll
    for (int m = 0; m < 8; ++m) {
        float4 xv = xrow4[ln + m * 64];
        if (wid == 0) s_xc4[ln + m * 64] = xv;
        float4 kk, vx;
        kk.x = __fadd_rn(__fmul_rn(xv.x, Wk), bk);
        kk.y = __fadd_rn(__fmul_rn(xv.y, Wk), bk);
        kk.z = __fadd_rn(__fmul_rn(xv.z, Wk), bk);
        kk.w = __fadd_rn(__fmul_rn(xv.w, Wk), bk);
        vx.x = __fadd_rn(__fmul_rn(xv.x, Wv), bv);
        vx.y = __fadd_rn(__fmul_rn(xv.y, Wv), bv);
        vx.z = __fadd_rn(__fmul_rn(xv.z, Wv), bv);
        vx.w = __fadd_rn(__fmul_rn(xv.w, Wv), bv);
        kv[m] = kk; vv[m] = vx;
        vsum += vx.x + vx.y + vx.z + vx.w;
        kmx = fmaxf(kmx, fmaxf(fmaxf(kk.x, kk.y), fmaxf(kk.z, kk.w)));
        kmn = fminf(kmn, fminf(fminf(kk.x, kk.y), fminf(kk.z, kk.w)));
    }
    vsum = waveSum(vsum);
    kmx  = waveMax(kmx);
    kmn  = waveMin(kmn);
    const float vmean = vsum * (1.f / (float)LL);

    // ---- step 2: per-wave top-40 over its 512-element range (MT coalesced)
    const int lbase = wid * 512 + ln;
    float mloc[8];
#pragma unroll
    for (int j = 0; j < 8; ++j) mloc[j] = Mrow[lbase + 64 * j];

    float wbv = mloc[0]; int wbi = lbase;
#pragma unroll
    for (int j = 1; j < 8; ++j)
        if (mloc[j] > wbv) { wbv = mloc[j]; wbi = lbase + 64 * j; }

    for (int t = 0; t < UU; ++t) {
        float rv = wbv; int ri = wbi;
#pragma unroll
        for (int off = 1; off < 64; off <<= 1) {
            float ov = __shfl_xor(rv, off, 64);
            int   oi = __shfl_xor(ri, off, 64);
            if (ov > rv || (ov == rv && oi < ri)) { rv = ov; ri = oi; }
        }
        if (ln == 0) { s_cv[wid * UU + t] = rv; s_ci[wid * UU + t] = ri; }
        if (wbi == ri) {   // owner: invalidate + rescan
#pragma unroll
            for (int j = 0; j < 8; ++j) if (lbase + 64 * j == ri) mloc[j] = -3.4e38f;
            wbv = mloc[0]; wbi = lbase;
#pragma unroll
            for (int j = 1; j < 8; ++j)
                if (mloc[j] > wbv) { wbv = mloc[j]; wbi = lbase + 64 * j; }
        }
    }
    __syncthreads();

    // ---- step 3: merge 4x40 candidates -> global top-40 (wave 0)
    if (wid == 0) {
        float c0v = s_cv[ln],      c1v = s_cv[ln + 64];
        int   c0i = s_ci[ln],      c1i = s_ci[ln + 64];
        float c2v = (ln < 32) ? s_cv[ln + 128] : -3.4e38f;
        int   c2i = (ln < 32) ? s_ci[ln + 128] : (LL + 1);
        for (int t = 0; t < UU; ++t) {
            float rv = c0v; int ri = c0i;
            if (c1v > rv || (c1v == rv && c1i < ri)) { rv = c1v; ri = c1i; }
            if (c2v > rv || (c2v == rv && c2i < ri)) { rv = c2v; ri = c2i; }
#pragma unroll
            for (int off = 1; off < 64; off <<= 1) {
                float ov = __shfl_xor(rv, off, 64);
                int   oi = __shfl_xor(ri, off, 64);
                if (ov > rv || (ov == rv && oi < ri)) { rv = ov; ri = oi; }
            }
            if (ln == 0) s_top[t] = ri;
            if (c0i == ri) c0v = -3.4e38f;
            else if (c1i == ri) c1v = -3.4e38f;
            else if (c2i == ri) c2v = -3.4e38f;
        }
    }
    __syncthreads();

    // ---- step 4: upd[u] = softmax(q_p * k) . v — registers only, one u per wave
    for (int r = 0; r < UU / NW; ++r) {
        const int u = r * NW + wid;
        const int p = s_top[u];
        const float qp = __fadd_rn(__fmul_rn(s_xc[p], Wq), bq);
        const float smax = (qp >= 0.f) ? __fmul_rn(qp, kmx) : __fmul_rn(qp, kmn);
        float se = 0.f, sev = 0.f;
#pragma unroll
        for (int m = 0; m < 8; ++m) {
            float4 kk = kv[m], vx = vv[m];
            float e0 = __expf(qp * kk.x - smax);
            float e1 = __expf(qp * kk.y - smax);
            float e2 = __expf(qp * kk.z - smax);
            float e3 = __expf(qp * kk.w - smax);
            se += e0 + e1 + e2 + e3;
            sev = fmaf(e0, vx.x, fmaf(e1, vx.y, fmaf(e2, vx.z, fmaf(e3, vx.w, sev))));
        }
        se  = waveSum(se);
        sev = waveSum(sev);
        if (ln == 0) s_upd[u] = sev / se;
    }
    __syncthreads();

    // ---- step 5: ctx = vmean, scatter upd
#pragma unroll
    for (int m = 0; m < 2; ++m)
        s_wk4[tid + m * 256] = make_float4(vmean, vmean, vmean, vmean);
    __syncthreads();
    if (tid < UU) s_wk[s_top[tid]] = s_upd[tid];
    __syncthreads();

    // ---- step 6: t = xc + ctx*Wo + bo; LN1
    float lsum = 0.f;
#pragma unroll
    for (int m = 0; m < 2; ++m) {
        const int f = tid + m * 256;
        float4 cx = s_wk4[f], xc = s_xc4[f], tv;
        tv.x = xc.x + __fadd_rn(__fmul_rn(cx.x, Wo), bo);
        tv.y = xc.y + __fadd_rn(__fmul_rn(cx.y, Wo), bo);
        tv.z = xc.z + __fadd_rn(__fmul_rn(cx.z, Wo), bo);
        tv.w = xc.w + __fadd_rn(__fmul_rn(cx.w, Wo), bo);
        s_wk4[f] = tv;
        lsum += tv.x + tv.y + tv.z + tv.w;
    }
    const float mean1 = blockSum(lsum, s_red) * (1.f / (float)LL);
    float lss = 0.f;
#pragma unroll
    for (int m = 0; m < 2; ++m) {
        float4 tv = s_wk4[tid + m * 256];
        float d0 = tv.x - mean1, d1 = tv.y - mean1, d2 = tv.z - mean1, d3 = tv.w - mean1;
        lss += d0 * d0 + d1 * d1 + d2 * d2 + d3 * d3;
    }
    const float var1 = blockSum(lss, s_red) * (1.f / (float)LL);
    const float rs1 = rsqrtf(var1 + EPSF);

    // ---- step 7: x1 -> gelu FFN -> z; LN2 -> out
    float lsum2 = 0.f;
#pragma unroll
    for (int m = 0; m < 2; ++m) {
        const int f = tid + m * 256;
        float4 tv = s_wk4[f], zz;
        {
            float x1 = (tv.x - mean1) * rs1 * g1 + be1;
            float a = x1 * w1 + b1;
            float y = 0.5f * a * (1.f + erff(a * 0.70710678118654752f));
            zz.x = x1 + (y * w2 + b2);
        }
        {
            float x1 = (tv.y - mean1) * rs1 * g1 + be1;
            float a = x1 * w1 + b1;
            float y = 0.5f * a * (1.f + erff(a * 0.70710678118654752f));
            zz.y = x1 + (y * w2 + b2);
        }
        {
            float x1 = (tv.z - mean1) * rs1 * g1 + be1;
            float a = x1 * w1 + b1;
            float y = 0.5f * a * (1.f + erff(a * 0.70710678118654752f));
            zz.z = x1 + (y * w2 + b2);
        }
        {
            float x1 = (tv.w - mean1) * rs1 * g1 + be1;
            float a = x1 * w1 + b1;
            float y = 0.5f * a * (1.f + erff(a * 0.70710678118654752f));
            zz.w = x1 + (y * w2 + b2);
        }
        s_wk4[f] = zz;
        lsum2 += zz.x + zz.y + zz.z + zz.w;
    }
    const float mean2 = blockSum(lsum2, s_red) * (1.f / (float)LL);
    float lss2 = 0.f;
#pragma unroll
    for (int m = 0; m < 2; ++m) {
        float4 zz = s_wk4[tid + m * 256];
        float d0 = zz.x - mean2, d1 = zz.y - mean2, d2 = zz.z - mean2, d3 = zz.w - mean2;
        lss2 += d0 * d0 + d1 * d1 + d2 * d2 + d3 * d3;
    }
    const float var2 = blockSum(lss2, s_red) * (1.f / (float)LL);
    const float rs2 = rsqrtf(var2 + EPSF);

#pragma unroll
    for (int m = 0; m < 2; ++m) {
        const int f = tid + m * 256;
        float4 zz = s_wk4[f], oo;
        oo.x = (zz.x - mean2) * rs2 * g2 + be2;
        oo.y = (zz.y - mean2) * rs2 * g2 + be2;
        oo.z = (zz.z - mean2) * rs2 * g2 + be2;
        oo.w = (zz.w - mean2) * rs2 * g2 + be2;
        orow4[f] = oo;
    }
}

// ---------------- fallback (strided, self-contained; only if ws too small) ----------------
__global__ __launch_bounds__(NT) void informer_fallback(
    const float* __restrict__ xin,
    const float* __restrict__ gWq, const float* __restrict__ gbq,
    const float* __restrict__ gWk, const float* __restrict__ gbk,
    const float* __restrict__ gWv, const float* __restrict__ gbv,
    const float* __restrict__ gWo, const float* __restrict__ gbo,
    const float* __restrict__ gw1, const float* __restrict__ gb1,
    const float* __restrict__ gw2, const float* __restrict__ gb2,
    const float* __restrict__ gg1, const float* __restrict__ gbe1,
    const float* __restrict__ gg2, const float* __restrict__ gbe2,
    const int* __restrict__ idx,
    float* __restrict__ outp)
{
    const int tid  = threadIdx.x;
    const int lane = tid & 63;
    const int wid  = tid >> 6;
    const int blk  = blockIdx.x;
    const int b    = blk >> 7;
    const int c    = blk & (CC - 1);

    __shared__ float  s_xc[LL];
    __shared__ float  s_kc[LL];
    __shared__ float  s_v[LL];
    __shared__ float  s_red[NW];
    __shared__ double s_cv[NW * UU];
    __shared__ int    s_ci[NW * UU];
    __shared__ int    s_top[UU];
    __shared__ float  s_upd[UU];

    const float Wq = *gWq, bq = *gbq, Wk = *gWk, bk = *gbk;
    const float Wv = *gWv, bv = *gbv, Wo = *gWo, bo = *gbo;
    const float w1 = *gw1, b1 = *gb1, w2 = *gw2, b2 = *gb2;
    const float g1 = *gg1, be1 = *gbe1, g2 = *gg2, be2 = *gbe2;

    const float* xrow = xin + (size_t)b * LL * CC + c;
    float* orow = outp + (size_t)b * LL * CC + c;

    float vsum = 0.f, kmn = 3.4e38f, kmx = -3.4e38f;
    for (int l = tid; l < LL; l += NT) {
        float xv = xrow[(size_t)l * CC];
        s_xc[l] = xv;
        float kvv = __fadd_rn(__fmul_rn(xv, Wk), bk);
        float vvv = __fadd_rn(__fmul_rn(xv, Wv), bv);
        s_kc[l] = kvv;
        s_v[l] = vvv;
        vsum += vvv;
        kmn = fminf(kmn, kvv);
        kmx = fmaxf(kmx, kvv);
    }
    const float vmean  = blockSum(vsum, s_red) * (1.f / (float)LL);
    float t1 = waveMax(kmx);
    __syncthreads();
    if (lane == 0) s_red[wid] = t1;
    __syncthreads();
    const float kmxAll = fmaxf(fmaxf(s_red[0], s_red[1]), fmaxf(s_red[2], s_red[3]));
    float t2 = waveMin(kmn);
    __syncthreads();
    if (lane == 0) s_red[wid] = t2;
    __syncthreads();
    const float kmnAll = fminf(fminf(s_red[0], s_red[1]), fminf(s_red[2], s_red[3]));

    double mloc[8];
#pragma unroll
    for (int j = 0; j < 8; ++j) {
        const int l = tid + NT * j;
        const float qv = __fadd_rn(__fmul_rn(s_xc[l], Wq), bq);
        const double qd = (double)qv;
        const int* row = idx + l * UU;
        float kmaxs = -3.4e38f, kmins = 3.4e38f;
        double ssum = 0.0;
#pragma unroll 8
        for (int u = 0; u < UU; ++u) {
            float kvv = s_kc[row[u]];
            kmaxs = fmaxf(kmaxs, kvv);
            kmins = fminf(kmins, kvv);
            ssum += (double)kvv;
        }
        double qmax = (qd >= 0.0) ? qd * (double)kmaxs : qd * (double)kmins;
        mloc[j] = qmax - qd * ssum * (1.0 / (double)LL);
    }

    double wbv = mloc[0]; int wbi = tid;
#pragma unroll
    for (int j = 1; j < 8; ++j)
        if (mloc[j] > wbv) { wbv = mloc[j]; wbi = tid + NT * j; }

    for (int t = 0; t < UU; ++t) {
        double rv = wbv; int ri = wbi;
#pragma unroll
        for (int off = 1; off < 64; off <<= 1) {
            double ov = __shfl_xor(rv, off, 64);
            int    oi = __shfl_xor(ri, off, 64);
            if (ov > rv || (ov == rv && oi < ri)) { rv = ov; ri = oi; }
        }
        if (lane == 0) { s_cv[wid * UU + t] = rv; s_ci[wid * UU + t] = ri; }
        if (wbi == ri) {
#pragma unroll
            for (int j = 0; j < 8; ++j) if ((tid + NT * j) == ri) mloc[j] = -1e300;
            wbv = mloc[0]; wbi = tid;
#pragma unroll
            for (int j = 1; j < 8; ++j)
                if (mloc[j] > wbv) { wbv = mloc[j]; wbi = tid + NT * j; }
        }
    }
    __syncthreads();

    if (wid == 0) {
        double c0v = s_cv[lane], c1v = s_cv[lane + 64];
        int    c0i = s_ci[lane], c1i = s_ci[lane + 64];
        double c2v = (lane < 32) ? s_cv[lane + 128] : -1e300;
        int    c2i = (lane < 32) ? s_ci[lane + 128] : (LL + 1);
        for (int t = 0; t < UU; ++t) {
            double rv = c0v; int ri = c0i;
            if (c1v > rv || (c1v == rv && c1i < ri)) { rv = c1v; ri = c1i; }
            if (c2v > rv || (c2v == rv && c2i < ri)) { rv = c2v; ri = c2i; }
#pragma unroll
            for (int off = 1; off < 64; off <<= 1) {
                double ov = __shfl_xor(rv, off, 64);
                int    oi = __shfl_xor(ri, off, 64);
                if (ov > rv || (ov == rv && oi < ri)) { rv = ov; ri = oi; }
            }
            if (lane == 0) s_top[t] = ri;
            if (c0i == ri) c0v = -1e300;
            else if (c1i == ri) c1v = -1e300;
            else if (c2i == ri) c2v = -1e300;
        }
    }
    __syncthreads();

    for (int r = 0; r < UU / NW; ++r) {
        const int u = r * NW + wid;
        const int p = s_top[u];
        const float qp = __fadd_rn(__fmul_rn(s_xc[p], Wq), bq);
        const float smax = (qp >= 0.f) ? qp * kmxAll : qp * kmnAll;
        float se = 0.f, sev = 0.f;
        for (int l = lane; l < LL; l += 64) {
            float e = __expf(qp * s_kc[l] - smax);
            se += e;
            sev = fmaf(e, s_v[l], sev);
        }
        se = waveSum(se); sev = waveSum(sev);
        if (lane == 0) s_upd[u] = sev / se;
    }
    __syncthreads();

    for (int l = tid; l < LL; l += NT) s_kc[l] = vmean;
    __syncthreads();
    if (tid < UU) s_kc[s_top[tid]] = s_upd[tid];
    __syncthreads();

    float lsum = 0.f;
    for (int l = tid; l < LL; l += NT) {
        float tv = s_xc[l] + __fadd_rn(__fmul_rn(s_kc[l], Wo), bo);
        s_kc[l] = tv;
        lsum += tv;
    }
    const float mean1 = blockSum(lsum, s_red) * (1.f / (float)LL);
    float lss = 0.f;
    for (int l = tid; l < LL; l += NT) { float d = s_kc[l] - mean1; lss += d * d; }
    const float var1 = blockSum(lss, s_red) * (1.f / (float)LL);
    const float rs1 = rsqrtf(var1 + EPSF);

    float lsum2 = 0.f;
    for (int l = tid; l < LL; l += NT) {
        float x1 = (s_kc[l] - mean1) * rs1 * g1 + be1;
        float a  = x1 * w1 + b1;
        float y  = 0.5f * a * (1.f + erff(a * 0.70710678118654752f));
        y = y * w2 + b2;
        float z = x1 + y;
        s_kc[l] = z;
        lsum2 += z;
    }
    const float mean2 = blockSum(lsum2, s_red) * (1.f / (float)LL);
    float lss2 = 0.f;
    for (int l = tid; l < LL; l += NT) { float d = s_kc[l] - mean2; lss2 += d * d; }
    const float var2 = blockSum(lss2, s_red) * (1.f / (float)LL);
    const float rs2 = rsqrtf(var2 + EPSF);

    for (int l = tid; l < LL; l += NT)
        orow[(size_t)l * CC] = (s_kc[l] - mean2) * rs2 * g2 + be2;
}

extern "C" void kernel_launch(void* const* d_in, const int* in_sizes, int n_in,
                              void* d_out, int out_size, void* d_ws, size_t ws_size,
                              hipStream_t stream) {
    const float* x   = (const float*)d_in[0];
    const float* Wq  = (const float*)d_in[1];
    const float* bq  = (const float*)d_in[2];
    const float* Wk  = (const float*)d_in[3];
    const float* bk  = (const float*)d_in[4];
    const float* Wv  = (const float*)d_in[5];
    const float* bv  = (const float*)d_in[6];
    const float* Wo  = (const float*)d_in[7];
    const float* bo  = (const float*)d_in[8];
    const float* w1  = (const float*)d_in[9];
    const float* b1  = (const float*)d_in[10];
    const float* w2  = (const float*)d_in[11];
    const float* b2  = (const float*)d_in[12];
    const float* g1  = (const float*)d_in[13];
    const float* be1 = (const float*)d_in[14];
    const float* g2  = (const float*)d_in[15];
    const float* be2 = (const float*)d_in[16];
    const int*   idx = (const int*)d_in[17];
    float* out = (float*)d_out;

    const size_t SZ = (size_t)BB * LL * CC * sizeof(float);  // 16 MB

    if (ws_size >= 2 * SZ) {
        float* xT = (float*)d_ws;
        float* MT = (float*)((char*)d_ws + SZ);   // becomes outT in-place
        // 1) M[B,L,C] into d_out (coalesced writes)
        agg_kernel<<<dim3((LL / 8) * BB), dim3(256), 0, stream>>>(x, idx, Wq, bq, Wk, bk, out);
        // 2) transpose x->xT and M->MT in one launch
        transpose_dual<<<dim3(CC / 32, LL / 32, 2 * BB), dim3(32, 8), 0, stream>>>(x, xT, out, MT);
        // 3) main: reads xT+MT, overwrites MT rows with output
        informer_main<<<dim3(BB * CC), dim3(NT), 0, stream>>>(
            xT, MT, Wq, bq, Wk, bk, Wv, bv, Wo, bo, w1, b1, w2, b2,
            g1, be1, g2, be2);
        // 4) transpose back into d_out
        transpose_out<<<dim3(LL / 32, CC / 32, BB), dim3(32, 8), 0, stream>>>(MT, out);
    } else {
        informer_fallback<<<dim3(BB * CC), dim3(NT), 0, stream>>>(
            x, Wq, bq, Wk, bk, Wv, bv, Wo, bo, w1, b1, w2, b2,
            g1, be1, g2, be2, idx, out);
    }
}